// Round 7
// baseline (330.825 us; speedup 1.0000x reference)
//
#include <hip/hip_runtime.h>
#include <cstdint>
#include <cstddef>

#define E_DIM   1024
#define B_DIM   1024
#define T_STEPS 10
#define OUT_DIM 34
#define OUT_PAD 48
#define HSTR    24            // h-transpose LDS row stride (16 cols + pad)
#define EK      128           // k-elements per W eighth-slice
#define WE_ELEMS (64 * EK)    // 8192 elems = 16 KB per buffer
#define DYN_LDS (2 * WE_ELEMS * 2 + 128 * HSTR * 2)   // 32768 + 6144 = 38912 B
#define LDP     40

typedef __attribute__((ext_vector_type(4))) float  f32x4;
typedef __attribute__((ext_vector_type(8))) __bf16 bf16x8;

__device__ __forceinline__ unsigned short f2bf(float f) {
    unsigned int u = __float_as_uint(f);
    u = (u + 0x7FFFu + ((u >> 16) & 1u)) >> 16;   // round-to-nearest-even
    return (unsigned short)u;
}
__device__ __forceinline__ float sigmoid_(float x) { return 1.0f / (1.0f + __expf(-x)); }
__device__ __forceinline__ float tanh_(float x)    { return 2.0f / (1.0f + __expf(-2.0f * x)) - 1.0f; }

// Weights in MFMA-B-fragment order: WF[bn(64)][E(8)][ks8(4)][nt(4)][lane(64)][8]
// frag elem: gate nt, e = bn*16 + (lane&15); k = E*128 + ks8*32 + (lane>>4)*8 + e8.
// lstm_step staging = linear copy; B-read = base + lane*16B + imm offset.
__global__ void prep_weights_frag(const float* __restrict__ W_ih, const float* __restrict__ W_hh,
                                  unsigned short* __restrict__ WsumF, unsigned short* __restrict__ WhhF) {
    const int bn = blockIdx.x >> 3, E = blockIdx.x & 7;
    const int nt = threadIdx.x >> 6, lane = threadIdx.x & 63;
    const int j = lane & 15, q = lane >> 4;
    const int srow = nt * E_DIM + bn * 16 + j;
    const float* wi = W_ih + (size_t)srow * E_DIM;
    const float* wh = W_hh + (size_t)srow * E_DIM;
    const size_t dstb = (size_t)bn * 65536 + (size_t)E * 8192 + nt * 512 + lane * 8;
#pragma unroll
    for (int ks8 = 0; ks8 < 4; ++ks8) {
        const int k = E * 128 + ks8 * 32 + q * 8;
        float4 i0 = *(const float4*)(wi + k);
        float4 i1 = *(const float4*)(wi + k + 4);
        float4 h0 = *(const float4*)(wh + k);
        float4 h1 = *(const float4*)(wh + k + 4);
        unsigned short s[8], hh[8];
        s[0] = f2bf(i0.x + h0.x); s[1] = f2bf(i0.y + h0.y);
        s[2] = f2bf(i0.z + h0.z); s[3] = f2bf(i0.w + h0.w);
        s[4] = f2bf(i1.x + h1.x); s[5] = f2bf(i1.y + h1.y);
        s[6] = f2bf(i1.z + h1.z); s[7] = f2bf(i1.w + h1.w);
        hh[0] = f2bf(h0.x); hh[1] = f2bf(h0.y); hh[2] = f2bf(h0.z); hh[3] = f2bf(h0.w);
        hh[4] = f2bf(h1.x); hh[5] = f2bf(h1.y); hh[6] = f2bf(h1.z); hh[7] = f2bf(h1.w);
        *(uint4*)(WsumF + dstb + ks8 * 2048) = *(const uint4*)s;
        *(uint4*)(WhhF  + dstb + ks8 * 2048) = *(const uint4*)hh;
    }
}

// h0 -> bf16 into hs slot 0; W_out -> bf16 padded to 48 rows; bias permuted
__global__ void prep_state(const float* __restrict__ h0, const float* __restrict__ W_out,
                           const float* __restrict__ b_ih, const float* __restrict__ b_hh,
                           unsigned short* __restrict__ hbuf, unsigned short* __restrict__ Woutp,
                           float* __restrict__ bperm) {
    const int b = blockIdx.x;
    const int t = threadIdx.x;
    if (b < 1024) {
        const size_t i = ((size_t)b * 256 + t) * 4;
        float4 hv = *(const float4*)(h0 + i);
        hbuf[i + 0] = f2bf(hv.x);
        hbuf[i + 1] = f2bf(hv.y);
        hbuf[i + 2] = f2bf(hv.z);
        hbuf[i + 3] = f2bf(hv.w);
    } else if (b < 1072) {
        const int o = b - 1024;                     // 0..47
        const int k = t * 4;
        float4 w = make_float4(0.f, 0.f, 0.f, 0.f);
        if (o < OUT_DIM) w = *(const float4*)(W_out + (size_t)o * E_DIM + k);
        const size_t dst = (size_t)o * E_DIM + k;
        Woutp[dst + 0] = f2bf(w.x);
        Woutp[dst + 1] = f2bf(w.y);
        Woutp[dst + 2] = f2bf(w.z);
        Woutp[dst + 3] = f2bf(w.w);
    } else {
        const int n = (b - 1072) * 256 + t;         // 0..4095
        const int g = (n >> 4) & 3;
        const int e = ((n >> 6) << 4) | (n & 15);
        const int srow = g * E_DIM + e;
        bperm[n] = b_ih[srow] + b_hh[srow];
    }
}

// Permute initial c into the MFMA-accumulator-native flat layout used by lstm_step:
// idx = (((bn*8+bm)*4 + wave)*64 + lane)*8 + mt*4 + r
// with m = bm*128 + wave*32 + mt*16 + q*4 + r, e = bn*16 + j, lane = q*16+j.
__global__ void prep_c(const float* __restrict__ c0, float* __restrict__ C) {
    const int m = blockIdx.x;
    const int e0 = threadIdx.x * 4;
    float4 v = *(const float4*)(c0 + (size_t)m * E_DIM + e0);
    const int bm = m >> 7, wave = (m >> 5) & 3, mt = (m >> 4) & 1, q = (m >> 2) & 3, r = m & 3;
    const float vv[4] = {v.x, v.y, v.z, v.w};
#pragma unroll
    for (int ii = 0; ii < 4; ++ii) {
        const int e = e0 + ii;
        const int bn = e >> 4, j = e & 15;
        const int lane = q * 16 + j;
        C[(((size_t)(bn * 8 + bm) * 4 + wave) * 64 + lane) * 8 + mt * 4 + r] = vv[ii];
    }
}

// One fused LSTM step. Grid (64, 8) = 512 blocks, 256 threads = 4 waves.
// K in 8 eighths of 128. Per eighth: block-issue next-eighth A loads (double-banked
// registers, no rolling ring -> one relaxed vmcnt, not per-iteration drains) + next
// W-slice loads; MFMA burst reads current bank + ping-pong LDS W buffer.
__global__ __launch_bounds__(256, 2) void lstm_step(
    const unsigned short* __restrict__ WF,   // [64][8][4][4][64][8] bf16 fragment-order
    const float* __restrict__ bp,            // [4096] permuted bias
    const unsigned short* __restrict__ Hin,  // [1024][1024] bf16
    float* __restrict__ C,                   // [B*E] f32 cell state in MFMA layout
    unsigned short* __restrict__ Hout)       // [1024][1024] bf16
{
    extern __shared__ __align__(16) unsigned short smem[];
    unsigned short* Wb[2] = { smem, smem + WE_ELEMS };   // 2 x 16 KB
    unsigned short* Ht    = smem + 2 * WE_ELEMS;         // 128 x HSTR (6 KB)

    const int tid  = threadIdx.x;
    const int wave = tid >> 6;
    const int lane = tid & 63;
    const int bn = blockIdx.x;
    const int bm = blockIdx.y;
    const int j  = lane & 15;
    const int q  = lane >> 4;

    f32x4 acc[2][4];
#pragma unroll
    for (int a = 0; a < 2; ++a)
#pragma unroll
        for (int b = 0; b < 4; ++b) acc[a][b] = (f32x4){0.f, 0.f, 0.f, 0.f};

    // hoisted far-from-use loads: biases + old cell state
    const int nb = bn * 64 + j;
    const float bi = bp[nb +  0];
    const float bf = bp[nb + 16];
    const float bg = bp[nb + 32];
    const float bo = bp[nb + 48];
    const size_t cbase = (((size_t)(bn * 8 + bm) * 4 + wave) * 64 + lane) * 8;
    float4 cold0 = *(const float4*)(C + cbase);
    float4 cold1 = *(const float4*)(C + cbase + 4);

    // A row base (per mt): m = bm*128 + wave*32 + mt*16 + j
    const unsigned short* arow0 = Hin + (size_t)(bm * 128 + wave * 32 + j) * E_DIM + q * 8;
    const unsigned short* arow1 = arow0 + (size_t)16 * E_DIM;
    const unsigned short* wsrc  = WF + (size_t)bn * 65536;    // this block's 128 KB slice

    // double-banked A registers: bank [E&1] holds eighth E's 4 k-steps x 2 mt
    uint4 ra[2][4][2];
    uint4 wreg[4];

    // preload eighth 0: A bank0 + W slice 0 -> Wb[0]
#pragma unroll
    for (int s = 0; s < 4; ++s) {
        ra[0][s][0] = *(const uint4*)(arow0 + s * 32);
        ra[0][s][1] = *(const uint4*)(arow1 + s * 32);
    }
#pragma unroll
    for (int i = 0; i < 4; ++i)
        wreg[i] = *(const uint4*)(wsrc + (i * 256 + tid) * 8);
#pragma unroll
    for (int i = 0; i < 4; ++i)
        *(uint4*)(Wb[0] + (i * 256 + tid) * 8) = wreg[i];
    __syncthreads();

#pragma unroll
    for (int E = 0; E < 8; ++E) {
        const int cur = E & 1;
        // block-issue next eighth's loads (A bank 1-cur, W slice E+1)
        if (E < 7) {
#pragma unroll
            for (int s = 0; s < 4; ++s) {
                ra[1 - cur][s][0] = *(const uint4*)(arow0 + (E + 1) * EK + s * 32);
                ra[1 - cur][s][1] = *(const uint4*)(arow1 + (E + 1) * EK + s * 32);
            }
#pragma unroll
            for (int i = 0; i < 4; ++i)
                wreg[i] = *(const uint4*)(wsrc + (size_t)(E + 1) * WE_ELEMS + (i * 256 + tid) * 8);
        }
        // MFMA burst on current bank + current LDS buffer
        const unsigned short* wb = Wb[cur] + lane * 8;
#pragma unroll
        for (int ks8 = 0; ks8 < 4; ++ks8) {
            bf16x8 av0 = __builtin_bit_cast(bf16x8, ra[cur][ks8][0]);
            bf16x8 av1 = __builtin_bit_cast(bf16x8, ra[cur][ks8][1]);
            bf16x8 bv[4];
#pragma unroll
            for (int nt = 0; nt < 4; ++nt)
                bv[nt] = *(const bf16x8*)(wb + (ks8 * 4 + nt) * 512);   // imm offset
#pragma unroll
            for (int nt = 0; nt < 4; ++nt) {
                acc[0][nt] = __builtin_amdgcn_mfma_f32_16x16x32_bf16(av0, bv[nt], acc[0][nt], 0, 0, 0);
                acc[1][nt] = __builtin_amdgcn_mfma_f32_16x16x32_bf16(av1, bv[nt], acc[1][nt], 0, 0, 0);
            }
        }
        if (E < 7) {
            unsigned short* wn_ = Wb[1 - cur];
#pragma unroll
            for (int i = 0; i < 4; ++i)
                *(uint4*)(wn_ + (i * 256 + tid) * 8) = wreg[i];
            __syncthreads();
        }
    }

    // ---- Epilogue: nt is the gate index (i,f,g,o); lane-local LSTM update ----
    float4 cnew[2];
    const float coldv[2][4] = {{cold0.x, cold0.y, cold0.z, cold0.w},
                               {cold1.x, cold1.y, cold1.z, cold1.w}};
#pragma unroll
    for (int mt = 0; mt < 2; ++mt) {
#pragma unroll
        for (int r = 0; r < 4; ++r) {
            const float iv = sigmoid_(acc[mt][0][r] + bi);
            const float fv = sigmoid_(acc[mt][1][r] + bf);
            const float gv = tanh_(acc[mt][2][r] + bg);
            const float ov = sigmoid_(acc[mt][3][r] + bo);
            const float cn = fv * coldv[mt][r] + iv * gv;
            cnew[mt][r] = cn;
            const int rowl = wave * 32 + mt * 16 + q * 4 + r;   // 0..127
            Ht[rowl * HSTR + j] = f2bf(ov * tanh_(cn));
        }
    }
    *(float4*)(C + cbase)     = cnew[0];
    *(float4*)(C + cbase + 4) = cnew[1];
    __syncthreads();

    // coalesced h store: 2 threads per row, 16B each
    {
        const int row = tid >> 1, part = tid & 1;
        uint4 v = *(const uint4*)(Ht + row * HSTR + part * 8);
        *(uint4*)(Hout + (size_t)(bm * 128 + row) * E_DIM + bn * 16 + part * 8) = v;
    }
}

// Output projection: out[b,t,o] = hs[t+1][b][:] . Wo[o][:] + b_out[o]
__global__ __launch_bounds__(256) void proj_kernel(
    const unsigned short* __restrict__ Hs,   // [T][B][E] bf16 (slot 1 of hs)
    const unsigned short* __restrict__ Wo,   // [48][E] bf16 (rows >=34 zero)
    const float* __restrict__ b_out,         // [34]
    float* __restrict__ Out)                 // [B][T][34]
{
    __shared__ float red[4][32][OUT_PAD];    // 24 KB

    const int tid = threadIdx.x, wave = tid >> 6, lane = tid & 63;
    const int j = lane & 15, q = lane >> 4;
    const int t  = blockIdx.y;
    const int bb = blockIdx.x;
    const unsigned short* Hbase = Hs + ((size_t)t * B_DIM + (size_t)bb * 32) * E_DIM;
    const int k0 = wave * 256;

    f32x4 acc[2][3];
#pragma unroll
    for (int a = 0; a < 2; ++a)
#pragma unroll
        for (int b = 0; b < 3; ++b) acc[a][b] = (f32x4){0.f, 0.f, 0.f, 0.f};

#pragma unroll
    for (int kk = 0; kk < 256; kk += 32) {
        const int kc = k0 + kk + q * 8;
        bf16x8 av[2], bv[3];
#pragma unroll
        for (int mt = 0; mt < 2; ++mt)
            av[mt] = *(const bf16x8*)(Hbase + (size_t)(mt * 16 + j) * E_DIM + kc);
#pragma unroll
        for (int nt = 0; nt < 3; ++nt)
            bv[nt] = *(const bf16x8*)(Wo + (size_t)(nt * 16 + j) * E_DIM + kc);
#pragma unroll
        for (int mt = 0; mt < 2; ++mt)
#pragma unroll
            for (int nt = 0; nt < 3; ++nt)
                acc[mt][nt] = __builtin_amdgcn_mfma_f32_16x16x32_bf16(av[mt], bv[nt], acc[mt][nt], 0, 0, 0);
    }

#pragma unroll
    for (int mt = 0; mt < 2; ++mt)
#pragma unroll
        for (int nt = 0; nt < 3; ++nt)
#pragma unroll
            for (int r = 0; r < 4; ++r)
                red[wave][mt * 16 + q * 4 + r][nt * 16 + j] = acc[mt][nt][r];
    __syncthreads();

#pragma unroll
    for (int ii = 0; ii < 6; ++ii) {
        const int idx = tid * 6 + ii;            // 0..1535 = 32 rows x 48 outs
        const int row = idx / OUT_PAD, o = idx % OUT_PAD;
        if (o < OUT_DIM) {
            const float s = red[0][row][o] + red[1][row][o] + red[2][row][o] + red[3][row][o];
            Out[((size_t)(bb * 32 + row) * T_STEPS + t) * OUT_DIM + o] = s + b_out[o];
        }
    }
}

extern "C" void kernel_launch(void* const* d_in, const int* in_sizes, int n_in,
                              void* d_out, int out_size, void* d_ws, size_t ws_size,
                              hipStream_t stream) {
    (void)in_sizes; (void)n_in; (void)out_size; (void)ws_size;
    const float* h     = (const float*)d_in[0];
    const float* c     = (const float*)d_in[1];
    const float* W_ih  = (const float*)d_in[2];
    const float* W_hh  = (const float*)d_in[3];
    const float* b_ih  = (const float*)d_in[4];
    const float* b_hh  = (const float*)d_in[5];
    const float* W_out = (const float*)d_in[6];
    const float* b_out = (const float*)d_in[7];
    float* out = (float*)d_out;

    char* ws = (char*)d_ws;
    unsigned short* WsumF = (unsigned short*)(ws + 0);          //  8 MB fragment-order
    unsigned short* WhhF  = (unsigned short*)(ws + 8388608);    //  8 MB fragment-order
    float*          bperm = (float*)(ws + 16777216);            // 16 KB
    unsigned short* Woutp = (unsigned short*)(ws + 16842752);   // 96 KB
    float*          cbuf  = (float*)(ws + 16941056);            //  4 MB (MFMA layout)
    unsigned short* hs    = (unsigned short*)(ws + 21135360);   // 22 MB: slot0=h0, slots1..10

    prep_weights_frag<<<512, 256, 0, stream>>>(W_ih, W_hh, WsumF, WhhF);
    prep_state<<<1088, 256, 0, stream>>>(h, W_out, b_ih, b_hh, hs, Woutp, bperm);
    prep_c<<<1024, 256, 0, stream>>>(c, cbuf);

    // step 0: x = 0  ->  W_hh only; steps 1..9: x == h_prev -> fused W_ih + W_hh
    lstm_step<<<dim3(64, 8), 256, DYN_LDS, stream>>>(WhhF, bperm, hs, cbuf,
                                                     hs + (size_t)B_DIM * E_DIM);
    for (int t = 1; t < T_STEPS; ++t)
        lstm_step<<<dim3(64, 8), 256, DYN_LDS, stream>>>(WsumF, bperm,
                                                         hs + (size_t)t * B_DIM * E_DIM,
                                                         cbuf,
                                                         hs + (size_t)(t + 1) * B_DIM * E_DIM);

    proj_kernel<<<dim3(32, T_STEPS), 256, 0, stream>>>(hs + (size_t)B_DIM * E_DIM,
                                                       Woutp, b_out, out);
}